// Round 1
// baseline (5768.049 us; speedup 1.0000x reference)
//
#include <hip/hip_runtime.h>
#include <hip/hip_bf16.h>
#include <stdint.h>

// Problem constants
#define TT 4
#define BE 16
#define BB 64          // TT * BE
#define CC 512
#define NN 512
#define NH 8
#define GD 64          // CC / NH
#define NW 16          // NN/32 packed words per (b,c) row
#define TAU 0.5f
#define THRESH 1.0f
#define SCALE 0.125f
#define EPS 1e-5f

// ---------------------------------------------------------------------------
// Kernel 1 v2: 1x1-conv + BN + LIF -> bit-packed spikes.
// Change vs v1: register-prefetch + double-buffered LDS software pipeline
// (one barrier per k-step; global loads for step k+2 issued during step k's
// compute), and LDS inflated to 43008 B so exactly 3 blocks/CU fit ->
// grid 1536 = 2 EVEN rounds of 768 (no half-empty tail round).
// Block tile: 64 c-rows x 128 n-cols, 256 threads, micro-tile 4x8.
// ---------------------------------------------------------------------------
__global__ __launch_bounds__(256, 3) void conv_bn_lif_kernel(
    const float* __restrict__ x,      // [BB, CC, NN]
    const float* __restrict__ Wq,     // [CC, CC] (out, in)
    const float* __restrict__ Wk,
    const float* __restrict__ Wv,
    const float* __restrict__ bn_g,   // [4, CC]
    const float* __restrict__ bn_b,
    const float* __restrict__ bn_m,
    const float* __restrict__ bn_v,
    uint32_t* __restrict__ qp,        // [BB*CC, NW] packed
    uint32_t* __restrict__ kp,
    uint32_t* __restrict__ vp)
{
    // Double-buffered tiles. Ws stride 204 (16B-multiple, 2-way-max write
    // conflict) chosen to make total LDS = 16896 + 26112 = 43008 B:
    // 160KiB/43KB -> exactly 3 blocks/CU (even 2-round grid packing).
    __shared__ float Xs[2][16][132];
    __shared__ float Ws_s[2][16][204];

    const int tid = threadIdx.x;
    const int tx = tid & 15;          // col group
    const int ty = tid >> 4;          // row group: rows c0+4ty..+3
    const int n0 = blockIdx.x * 128;
    const int c0 = blockIdx.y * 64;
    const int z  = blockIdx.z;
    const int be = z & (BE - 1);
    const int w  = z >> 4;            // 0=q 1=k 2=v

    const float* W = (w == 0) ? Wq : (w == 1) ? Wk : Wv;
    uint32_t* outp = (w == 0) ? qp : (w == 1) ? kp : vp;

    float inv_c[4], add_c[4];
#pragma unroll
    for (int i = 0; i < 4; ++i) {
        int c = c0 + 4 * ty + i;
        float g = bn_g[w * CC + c];
        float b = bn_b[w * CC + c];
        float m = bn_m[w * CC + c];
        float v = bn_v[w * CC + c];
        float inv = g / sqrtf(v + EPS);
        inv_c[i] = inv;
        add_c[i] = b - m * inv;
    }

    float mem[4][8];
#pragma unroll
    for (int i = 0; i < 4; ++i)
#pragma unroll
        for (int j = 0; j < 8; ++j) mem[i][j] = 0.0f;

    // Staging thread mappings (constant across k0)
    const int wr  = tid >> 2;         // W row within tile (0..63)
    const int wkw = tid & 3;          // W float4 along K
    const int kkA = tid >> 5;         // X: kk 0..7 (s=0), 8+kkA (s=1)
    const int colA = tid & 31;        // X: float4 column

    const float* Wrow = W + (size_t)(c0 + wr) * CC + 4 * wkw;

    for (int t = 0; t < TT; ++t) {
        const int b = t * BE + be;
        const float* xb = x + (size_t)b * CC * NN + n0 + 4 * colA;

        // ---- prologue: fill buf0, prefetch k0=16 (latency exposed once/t) ----
        float4 xrA = *(const float4*)&xb[(size_t)kkA * NN];
        float4 xrB = *(const float4*)&xb[(size_t)(8 + kkA) * NN];
        float4 wv4 = *(const float4*)&Wrow[0];

        __syncthreads();   // protect buf0 against prev-t laggards
        *(float4*)&Xs[0][kkA][4 * colA] = xrA;
        *(float4*)&Xs[0][8 + kkA][4 * colA] = xrB;
        Ws_s[0][4 * wkw + 0][wr] = wv4.x;
        Ws_s[0][4 * wkw + 1][wr] = wv4.y;
        Ws_s[0][4 * wkw + 2][wr] = wv4.z;
        Ws_s[0][4 * wkw + 3][wr] = wv4.w;

        xrA = *(const float4*)&xb[(size_t)(16 + kkA) * NN];
        xrB = *(const float4*)&xb[(size_t)(24 + kkA) * NN];
        wv4 = *(const float4*)&Wrow[16];
        __syncthreads();

        float acc[4][8];
#pragma unroll
        for (int i = 0; i < 4; ++i)
#pragma unroll
            for (int j = 0; j < 8; ++j) acc[i][j] = 0.0f;

        int cur = 0;
        for (int k0 = 0; k0 < CC; k0 += 16) {
            // ---- compute current buffer ----
#pragma unroll
            for (int kk = 0; kk < 16; ++kk) {
                float4 av  = *(float4*)&Ws_s[cur][kk][4 * ty];     // broadcast
                float4 xlo = *(float4*)&Xs[cur][kk][4 * tx];
                float4 xhi = *(float4*)&Xs[cur][kk][64 + 4 * tx];
                const float a[4]  = {av.x, av.y, av.z, av.w};
                const float xl[4] = {xlo.x, xlo.y, xlo.z, xlo.w};
                const float xh[4] = {xhi.x, xhi.y, xhi.z, xhi.w};
#pragma unroll
                for (int i = 0; i < 4; ++i) {
#pragma unroll
                    for (int j = 0; j < 4; ++j) {
                        acc[i][j]     += a[i] * xl[j];
                        acc[i][4 + j] += a[i] * xh[j];
                    }
                }
            }
            // ---- write prefetched (k0+16) tile, issue loads for k0+32 ----
            if (k0 + 16 < CC) {
                const int nxt = cur ^ 1;
                *(float4*)&Xs[nxt][kkA][4 * colA] = xrA;     // vmcnt wait here
                *(float4*)&Xs[nxt][8 + kkA][4 * colA] = xrB;
                Ws_s[nxt][4 * wkw + 0][wr] = wv4.x;
                Ws_s[nxt][4 * wkw + 1][wr] = wv4.y;
                Ws_s[nxt][4 * wkw + 2][wr] = wv4.z;
                Ws_s[nxt][4 * wkw + 3][wr] = wv4.w;
                if (k0 + 32 < CC) {
                    xrA = *(const float4*)&xb[(size_t)(k0 + 32 + kkA) * NN];
                    xrB = *(const float4*)&xb[(size_t)(k0 + 40 + kkA) * NN];
                    wv4 = *(const float4*)&Wrow[k0 + 32];
                }
                __syncthreads();
                cur = nxt;
            }
        }

        // epilogue: BN + LIF -> two nibbles/row -> octet shfl-OR -> global word
#pragma unroll
        for (int i = 0; i < 4; ++i) {
            uint32_t nibLo = 0, nibHi = 0;
#pragma unroll
            for (int j = 0; j < 4; ++j) {
                float y = acc[i][j] * inv_c[i] + add_c[i];
                float m2 = mem[i][j] * TAU + y;
                bool s = m2 > THRESH;
                nibLo |= (s ? 1u : 0u) << j;
                mem[i][j] = s ? 0.0f : m2;

                float y2 = acc[i][4 + j] * inv_c[i] + add_c[i];
                float m22 = mem[i][4 + j] * TAU + y2;
                bool s2 = m22 > THRESH;
                nibHi |= (s2 ? 1u : 0u) << j;
                mem[i][4 + j] = s2 ? 0.0f : m22;
            }
            const size_t rowbase = (size_t)(b * CC + c0 + 4 * ty + i) * NW + (n0 >> 5);
            uint32_t wlo = nibLo << (4 * (tx & 7));
            wlo |= (uint32_t)__shfl_xor((int)wlo, 1);
            wlo |= (uint32_t)__shfl_xor((int)wlo, 2);
            wlo |= (uint32_t)__shfl_xor((int)wlo, 4);
            uint32_t whi = nibHi << (4 * (tx & 7));
            whi |= (uint32_t)__shfl_xor((int)whi, 1);
            whi |= (uint32_t)__shfl_xor((int)whi, 2);
            whi |= (uint32_t)__shfl_xor((int)whi, 4);
            if ((tx & 7) == 0) {
                outp[rowbase + (tx >> 3)] = wlo;
                outp[rowbase + 2 + (tx >> 3)] = whi;
            }
        }
    }
}

// ---------------------------------------------------------------------------
// Kernel 2: fused attention + LIF3 on packed spikes (unchanged, verified).
// ---------------------------------------------------------------------------
__global__ __launch_bounds__(256) void attn_lif_kernel(
    const uint32_t* __restrict__ qp,
    const uint32_t* __restrict__ kp,
    const uint32_t* __restrict__ vp,
    uint32_t* __restrict__ s3p)
{
    __shared__ uint32_t kL[64][NW + 1];
    __shared__ uint32_t vL[64][NW + 1];
    __shared__ float    Msh[64][64 + 1];
    __shared__ uint32_t qL[64][5];

    const int tid = threadIdx.x;
    const int nchunk = blockIdx.x;
    const int h = blockIdx.y;
    const int be = blockIdx.z;
    const int d_own = tid >> 2;
    const int nw_own = tid & 3;

    float mem[32];
#pragma unroll
    for (int i = 0; i < 32; ++i) mem[i] = 0.0f;

    for (int t = 0; t < TT; ++t) {
        const int b = t * BE + be;
        const size_t base_row = (size_t)(b * CC + h * GD);

        for (int i = tid; i < 64 * NW; i += 256) {
            int r = i >> 4;
            int w = i & (NW - 1);
            kL[r][w] = kp[(base_row + r) * NW + w];
            vL[r][w] = vp[(base_row + r) * NW + w];
        }
        {
            int r = tid >> 2;
            int w = tid & 3;
            qL[r][w] = qp[(base_row + r) * NW + nchunk * 4 + w];
        }
        __syncthreads();

        for (int e = tid; e < 64 * 64; e += 256) {
            int d = e >> 6;
            int dp = e & 63;
            int s = 0;
#pragma unroll
            for (int w = 0; w < NW; ++w) s += __popc(vL[d][w] & kL[dp][w]);
            Msh[d][dp] = (float)s;
        }
        __syncthreads();

        float acc[32];
#pragma unroll
        for (int i = 0; i < 32; ++i) acc[i] = 0.0f;

        for (int dp = 0; dp < 64; ++dp) {
            float Mv = Msh[d_own][dp];
            uint32_t w = qL[dp][nw_own];
#pragma unroll
            for (int b2 = 0; b2 < 32; ++b2) {
                acc[b2] += ((w >> b2) & 1u) ? Mv : 0.0f;
            }
        }

        uint32_t sw = 0;
#pragma unroll
        for (int b2 = 0; b2 < 32; ++b2) {
            float m2 = mem[b2] * TAU + SCALE * acc[b2];
            bool s = m2 > THRESH;
            sw |= (s ? 1u : 0u) << b2;
            mem[b2] = s ? 0.0f : m2;
        }
        s3p[(base_row + d_own) * NW + nchunk * 4 + nw_own] = sw;
        __syncthreads();
    }
}

// ---------------------------------------------------------------------------
// Kernel 3 v2: projection conv + BN on packed spikes -> fp32 output.
// Same pipelined double-buffer structure as kernel 1. VGPR capped at 128
// (__launch_bounds__(256,4)) + small LDS -> 4 blocks/CU -> grid 2048 =
// 2 EVEN rounds of 1024.
// ---------------------------------------------------------------------------
__global__ __launch_bounds__(256, 4) void proj_kernel(
    const uint32_t* __restrict__ s3p,          // [BB*CC, NW] packed
    const float* __restrict__ W,               // [CC, CC]
    const float* __restrict__ bn_g,
    const float* __restrict__ bn_b,
    const float* __restrict__ bn_m,
    const float* __restrict__ bn_v,
    float* __restrict__ out)                   // [BB, CC, NN]
{
    __shared__ float Xs[2][16][132];
    __shared__ float Ws_s[2][16][68];

    const int tid = threadIdx.x;
    const int tx = tid & 15;
    const int ty = tid >> 4;
    const int n0 = blockIdx.x * 128;
    const int c0 = blockIdx.y * 64;
    const int b = blockIdx.z;

    float inv_c[4], add_c[4];
#pragma unroll
    for (int i = 0; i < 4; ++i) {
        int c = c0 + 4 * ty + i;
        float g = bn_g[3 * CC + c];
        float bt = bn_b[3 * CC + c];
        float m = bn_m[3 * CC + c];
        float v = bn_v[3 * CC + c];
        float inv = g / sqrtf(v + EPS);
        inv_c[i] = inv;
        add_c[i] = bt - m * inv;
    }

    const int wr  = tid >> 2;
    const int wkw = tid & 3;
    const int kkA = tid >> 5;
    const int colA = tid & 31;
    const int shA = 4 * (colA & 7);

    const float* Wrow = W + (size_t)(c0 + wr) * CC + 4 * wkw;
    const uint32_t* sp = s3p + (size_t)(b * CC) * NW + (n0 >> 5) + (colA >> 3);

    float acc[4][8];
#pragma unroll
    for (int i = 0; i < 4; ++i)
#pragma unroll
        for (int j = 0; j < 8; ++j) acc[i][j] = 0.0f;

    // ---- prologue ----
    uint32_t swA = sp[(size_t)kkA * NW];
    uint32_t swB = sp[(size_t)(8 + kkA) * NW];
    float4 wv4 = *(const float4*)&Wrow[0];

    {
        float4 xv;
        xv.x = (float)((swA >> (shA + 0)) & 1u);
        xv.y = (float)((swA >> (shA + 1)) & 1u);
        xv.z = (float)((swA >> (shA + 2)) & 1u);
        xv.w = (float)((swA >> (shA + 3)) & 1u);
        *(float4*)&Xs[0][kkA][4 * colA] = xv;
        xv.x = (float)((swB >> (shA + 0)) & 1u);
        xv.y = (float)((swB >> (shA + 1)) & 1u);
        xv.z = (float)((swB >> (shA + 2)) & 1u);
        xv.w = (float)((swB >> (shA + 3)) & 1u);
        *(float4*)&Xs[0][8 + kkA][4 * colA] = xv;
        Ws_s[0][4 * wkw + 0][wr] = wv4.x;
        Ws_s[0][4 * wkw + 1][wr] = wv4.y;
        Ws_s[0][4 * wkw + 2][wr] = wv4.z;
        Ws_s[0][4 * wkw + 3][wr] = wv4.w;
    }
    swA = sp[(size_t)(16 + kkA) * NW];
    swB = sp[(size_t)(24 + kkA) * NW];
    wv4 = *(const float4*)&Wrow[16];
    __syncthreads();

    int cur = 0;
    for (int k0 = 0; k0 < CC; k0 += 16) {
#pragma unroll
        for (int kk = 0; kk < 16; ++kk) {
            float4 av  = *(float4*)&Ws_s[cur][kk][4 * ty];
            float4 xlo = *(float4*)&Xs[cur][kk][4 * tx];
            float4 xhi = *(float4*)&Xs[cur][kk][64 + 4 * tx];
            const float a[4]  = {av.x, av.y, av.z, av.w};
            const float xl[4] = {xlo.x, xlo.y, xlo.z, xlo.w};
            const float xh[4] = {xhi.x, xhi.y, xhi.z, xhi.w};
#pragma unroll
            for (int i = 0; i < 4; ++i) {
#pragma unroll
                for (int j = 0; j < 4; ++j) {
                    acc[i][j]     += a[i] * xl[j];
                    acc[i][4 + j] += a[i] * xh[j];
                }
            }
        }
        if (k0 + 16 < CC) {
            const int nxt = cur ^ 1;
            float4 xv;
            xv.x = (float)((swA >> (shA + 0)) & 1u);
            xv.y = (float)((swA >> (shA + 1)) & 1u);
            xv.z = (float)((swA >> (shA + 2)) & 1u);
            xv.w = (float)((swA >> (shA + 3)) & 1u);
            *(float4*)&Xs[nxt][kkA][4 * colA] = xv;
            xv.x = (float)((swB >> (shA + 0)) & 1u);
            xv.y = (float)((swB >> (shA + 1)) & 1u);
            xv.z = (float)((swB >> (shA + 2)) & 1u);
            xv.w = (float)((swB >> (shA + 3)) & 1u);
            *(float4*)&Xs[nxt][8 + kkA][4 * colA] = xv;
            Ws_s[nxt][4 * wkw + 0][wr] = wv4.x;
            Ws_s[nxt][4 * wkw + 1][wr] = wv4.y;
            Ws_s[nxt][4 * wkw + 2][wr] = wv4.z;
            Ws_s[nxt][4 * wkw + 3][wr] = wv4.w;
            if (k0 + 32 < CC) {
                swA = sp[(size_t)(k0 + 32 + kkA) * NW];
                swB = sp[(size_t)(k0 + 40 + kkA) * NW];
                wv4 = *(const float4*)&Wrow[k0 + 32];
            }
            __syncthreads();
            cur = nxt;
        }
    }

    float* ob = out + (size_t)b * CC * NN;
#pragma unroll
    for (int i = 0; i < 4; ++i) {
        int c = c0 + 4 * ty + i;
        float4 lo, hi;
        lo.x = acc[i][0] * inv_c[i] + add_c[i];
        lo.y = acc[i][1] * inv_c[i] + add_c[i];
        lo.z = acc[i][2] * inv_c[i] + add_c[i];
        lo.w = acc[i][3] * inv_c[i] + add_c[i];
        hi.x = acc[i][4] * inv_c[i] + add_c[i];
        hi.y = acc[i][5] * inv_c[i] + add_c[i];
        hi.z = acc[i][6] * inv_c[i] + add_c[i];
        hi.w = acc[i][7] * inv_c[i] + add_c[i];
        *(float4*)&ob[(size_t)c * NN + n0 + 4 * tx] = lo;
        *(float4*)&ob[(size_t)c * NN + n0 + 64 + 4 * tx] = hi;
    }
}

// ---------------------------------------------------------------------------
extern "C" void kernel_launch(void* const* d_in, const int* in_sizes, int n_in,
                              void* d_out, int out_size, void* d_ws, size_t ws_size,
                              hipStream_t stream) {
    const float* x     = (const float*)d_in[0];
    const float* wq    = (const float*)d_in[1];
    const float* wk    = (const float*)d_in[2];
    const float* wv    = (const float*)d_in[3];
    const float* wproj = (const float*)d_in[4];
    const float* bng   = (const float*)d_in[5];
    const float* bnb   = (const float*)d_in[6];
    const float* bnm   = (const float*)d_in[7];
    const float* bnv   = (const float*)d_in[8];

    const size_t PK = (size_t)BB * CC * NW;            // 2 MiB each
    uint32_t* qp  = (uint32_t*)d_ws;
    uint32_t* kp  = qp + PK;
    uint32_t* vp  = kp + PK;
    uint32_t* s3p = vp + PK;                           // total 8 MiB

    dim3 gconv(NN / 128, CC / 64, 3 * BE);             // z = w*16 + be
    conv_bn_lif_kernel<<<gconv, 256, 0, stream>>>(x, wq, wk, wv, bng, bnb, bnm, bnv,
                                                  qp, kp, vp);

    dim3 gattn(4, NH, BE);
    attn_lif_kernel<<<gattn, 256, 0, stream>>>(qp, kp, vp, s3p);

    dim3 gproj(NN / 128, CC / 64, BB);
    proj_kernel<<<gproj, 256, 0, stream>>>(s3p, wproj, bng, bnb, bnm, bnv, (float*)d_out);
}

// Round 2
// 1598.102 us; speedup vs baseline: 3.6093x; 3.6093x over previous
//
#include <hip/hip_runtime.h>
#include <hip/hip_bf16.h>
#include <stdint.h>

// Problem constants
#define TT 4
#define BE 16
#define BB 64          // TT * BE
#define CC 512
#define NN 512
#define NH 8
#define GD 64          // CC / NH
#define NW 16          // NN/32 packed words per (b,c) row
#define TAU 0.5f
#define THRESH 1.0f
#define SCALE 0.125f
#define EPS 1e-5f

// Direct global->LDS DMA, 16B per lane. LDS dest is wave-uniform base +
// lane*16 (linear); global src is per-lane.
#define GLL16(g, l)                                                        \
    __builtin_amdgcn_global_load_lds(                                      \
        (const __attribute__((address_space(1))) void*)(g),                \
        (__attribute__((address_space(3))) void*)(l), 16, 0, 0)

// ---------------------------------------------------------------------------
// Kernel 1 v3: 1x1-conv + BN + LIF -> bit-packed spikes.
// vs v1 (775us): X staged via global_load_lds (no VGPR round-trip),
// double-buffered LDS, ONE barrier per k-step, next-tile loads issued before
// current-tile compute (latency hidden under ~1024 FMA cycles).
// vs v2 (5690us disaster): NO __launch_bounds__ second arg (it capped VGPR at
// 84 -> 16GB scratch spill). Natural allocation gave 128 VGPR = 4 blocks/CU.
// Block tile: 64 c-rows x 128 n-cols, 256 threads, micro-tile 4x8.
// ---------------------------------------------------------------------------
__global__ __launch_bounds__(256) void conv_bn_lif_kernel(
    const float* __restrict__ x,      // [BB, CC, NN]
    const float* __restrict__ Wq,     // [CC, CC] (out, in)
    const float* __restrict__ Wk,
    const float* __restrict__ Wv,
    const float* __restrict__ bn_g,   // [4, CC]
    const float* __restrict__ bn_b,
    const float* __restrict__ bn_m,
    const float* __restrict__ bn_v,
    uint32_t* __restrict__ qp,        // [BB*CC, NW] packed
    uint32_t* __restrict__ kp,
    uint32_t* __restrict__ vp)
{
    // Xs UNPADDED [16][128]: required linear for global_load_lds lane order.
    // Reads are float4 at 4*tx (+64): 2-way bank aliasing max = free.
    __shared__ float Xs[2][16][128];
    __shared__ float Ws_s[2][16][68];

    const int tid = threadIdx.x;
    const int tx = tid & 15;          // col group
    const int ty = tid >> 4;          // row group: rows c0+4ty..+3
    const int n0 = blockIdx.x * 128;
    const int c0 = blockIdx.y * 64;
    const int z  = blockIdx.z;
    const int be = z & (BE - 1);
    const int w  = z >> 4;            // 0=q 1=k 2=v

    const float* W = (w == 0) ? Wq : (w == 1) ? Wk : Wv;
    uint32_t* outp = (w == 0) ? qp : (w == 1) ? kp : vp;

    float inv_c[4], add_c[4];
#pragma unroll
    for (int i = 0; i < 4; ++i) {
        int c = c0 + 4 * ty + i;
        float g = bn_g[w * CC + c];
        float b = bn_b[w * CC + c];
        float m = bn_m[w * CC + c];
        float v = bn_v[w * CC + c];
        float inv = g / sqrtf(v + EPS);
        inv_c[i] = inv;
        add_c[i] = b - m * inv;
    }

    float mem[4][8];
#pragma unroll
    for (int i = 0; i < 4; ++i)
#pragma unroll
        for (int j = 0; j < 8; ++j) mem[i][j] = 0.0f;

    // W staging mapping (reg->LDS transpose; can't use gll for transposes)
    const int wr  = tid >> 2;         // W row within tile (0..63)
    const int wkw = tid & 3;          // W float4 along K
    const float* Wrow = W + (size_t)(c0 + wr) * CC + 4 * wkw;

    // X gll mapping: wave wid handles chunks {wid, wid+4}; chunk c = rows
    // {2c, 2c+1} of the k-tile; lane covers 16B at col 4*(lane&31).
    const int lane = tid & 63;
    const int wid  = tid >> 6;
    const int xrow0 = 2 * wid + (lane >> 5);   // s=0 global row offset
    const int xcol  = 4 * (lane & 31);

    for (int t = 0; t < TT; ++t) {
        const int b = t * BE + be;
        const float* xg = x + (size_t)b * CC * NN + n0 + xcol;

        // protect buf0 against prev-t laggards still reading it
        __syncthreads();

        // ---- prologue: stage k0=0 into buf0 ----
        GLL16(xg + (size_t)xrow0 * NN,       &Xs[0][2 * wid][0]);
        GLL16(xg + (size_t)(xrow0 + 8) * NN, &Xs[0][8 + 2 * wid][0]);
        {
            float4 wv4 = *(const float4*)&Wrow[0];
            Ws_s[0][4 * wkw + 0][wr] = wv4.x;
            Ws_s[0][4 * wkw + 1][wr] = wv4.y;
            Ws_s[0][4 * wkw + 2][wr] = wv4.z;
            Ws_s[0][4 * wkw + 3][wr] = wv4.w;
        }
        __syncthreads();   // drains vmcnt (gll) + lgkm (ds_write): buf0 ready

        float acc[4][8];
#pragma unroll
        for (int i = 0; i < 4; ++i)
#pragma unroll
            for (int j = 0; j < 8; ++j) acc[i][j] = 0.0f;

        int cur = 0;
        for (int k0 = 0; k0 < CC; k0 += 16) {
            const int nxt = cur ^ 1;
            float4 wv4;
            if (k0 + 16 < CC) {
                // issue next tile's loads BEFORE compute: X direct to LDS
                // (buf[nxt] reads were sealed by the previous barrier)
                GLL16(xg + (size_t)(k0 + 16 + xrow0) * NN,
                      &Xs[nxt][2 * wid][0]);
                GLL16(xg + (size_t)(k0 + 24 + xrow0) * NN,
                      &Xs[nxt][8 + 2 * wid][0]);
                wv4 = *(const float4*)&Wrow[k0 + 16];
            }

            // ---- compute current buffer ----
#pragma unroll
            for (int kk = 0; kk < 16; ++kk) {
                float4 av  = *(float4*)&Ws_s[cur][kk][4 * ty];     // broadcast
                float4 xlo = *(float4*)&Xs[cur][kk][4 * tx];
                float4 xhi = *(float4*)&Xs[cur][kk][64 + 4 * tx];
                const float a[4]  = {av.x, av.y, av.z, av.w};
                const float xl[4] = {xlo.x, xlo.y, xlo.z, xlo.w};
                const float xh[4] = {xhi.x, xhi.y, xhi.z, xhi.w};
#pragma unroll
                for (int i = 0; i < 4; ++i) {
#pragma unroll
                    for (int j = 0; j < 4; ++j) {
                        acc[i][j]     += a[i] * xl[j];
                        acc[i][4 + j] += a[i] * xh[j];
                    }
                }
            }

            if (k0 + 16 < CC) {
                Ws_s[nxt][4 * wkw + 0][wr] = wv4.x;
                Ws_s[nxt][4 * wkw + 1][wr] = wv4.y;
                Ws_s[nxt][4 * wkw + 2][wr] = wv4.z;
                Ws_s[nxt][4 * wkw + 3][wr] = wv4.w;
                __syncthreads();   // vmcnt+lgkm drain: buf[nxt] ready
                cur = nxt;
            }
        }

        // epilogue: BN + LIF -> two nibbles/row -> octet shfl-OR -> global word
#pragma unroll
        for (int i = 0; i < 4; ++i) {
            uint32_t nibLo = 0, nibHi = 0;
#pragma unroll
            for (int j = 0; j < 4; ++j) {
                float y = acc[i][j] * inv_c[i] + add_c[i];
                float m2 = mem[i][j] * TAU + y;
                bool s = m2 > THRESH;
                nibLo |= (s ? 1u : 0u) << j;
                mem[i][j] = s ? 0.0f : m2;

                float y2 = acc[i][4 + j] * inv_c[i] + add_c[i];
                float m22 = mem[i][4 + j] * TAU + y2;
                bool s2 = m22 > THRESH;
                nibHi |= (s2 ? 1u : 0u) << j;
                mem[i][4 + j] = s2 ? 0.0f : m22;
            }
            const size_t rowbase = (size_t)(b * CC + c0 + 4 * ty + i) * NW + (n0 >> 5);
            uint32_t wlo = nibLo << (4 * (tx & 7));
            wlo |= (uint32_t)__shfl_xor((int)wlo, 1);
            wlo |= (uint32_t)__shfl_xor((int)wlo, 2);
            wlo |= (uint32_t)__shfl_xor((int)wlo, 4);
            uint32_t whi = nibHi << (4 * (tx & 7));
            whi |= (uint32_t)__shfl_xor((int)whi, 1);
            whi |= (uint32_t)__shfl_xor((int)whi, 2);
            whi |= (uint32_t)__shfl_xor((int)whi, 4);
            if ((tx & 7) == 0) {
                outp[rowbase + (tx >> 3)] = wlo;
                outp[rowbase + 2 + (tx >> 3)] = whi;
            }
        }
    }
}

// ---------------------------------------------------------------------------
// Kernel 2: fused attention + LIF3 on packed spikes (unchanged, verified).
// ---------------------------------------------------------------------------
__global__ __launch_bounds__(256) void attn_lif_kernel(
    const uint32_t* __restrict__ qp,
    const uint32_t* __restrict__ kp,
    const uint32_t* __restrict__ vp,
    uint32_t* __restrict__ s3p)
{
    __shared__ uint32_t kL[64][NW + 1];
    __shared__ uint32_t vL[64][NW + 1];
    __shared__ float    Msh[64][64 + 1];
    __shared__ uint32_t qL[64][5];

    const int tid = threadIdx.x;
    const int nchunk = blockIdx.x;
    const int h = blockIdx.y;
    const int be = blockIdx.z;
    const int d_own = tid >> 2;
    const int nw_own = tid & 3;

    float mem[32];
#pragma unroll
    for (int i = 0; i < 32; ++i) mem[i] = 0.0f;

    for (int t = 0; t < TT; ++t) {
        const int b = t * BE + be;
        const size_t base_row = (size_t)(b * CC + h * GD);

        for (int i = tid; i < 64 * NW; i += 256) {
            int r = i >> 4;
            int w = i & (NW - 1);
            kL[r][w] = kp[(base_row + r) * NW + w];
            vL[r][w] = vp[(base_row + r) * NW + w];
        }
        {
            int r = tid >> 2;
            int w = tid & 3;
            qL[r][w] = qp[(base_row + r) * NW + nchunk * 4 + w];
        }
        __syncthreads();

        for (int e = tid; e < 64 * 64; e += 256) {
            int d = e >> 6;
            int dp = e & 63;
            int s = 0;
#pragma unroll
            for (int w = 0; w < NW; ++w) s += __popc(vL[d][w] & kL[dp][w]);
            Msh[d][dp] = (float)s;
        }
        __syncthreads();

        float acc[32];
#pragma unroll
        for (int i = 0; i < 32; ++i) acc[i] = 0.0f;

        for (int dp = 0; dp < 64; ++dp) {
            float Mv = Msh[d_own][dp];
            uint32_t w = qL[dp][nw_own];
#pragma unroll
            for (int b2 = 0; b2 < 32; ++b2) {
                acc[b2] += ((w >> b2) & 1u) ? Mv : 0.0f;
            }
        }

        uint32_t sw = 0;
#pragma unroll
        for (int b2 = 0; b2 < 32; ++b2) {
            float m2 = mem[b2] * TAU + SCALE * acc[b2];
            bool s = m2 > THRESH;
            sw |= (s ? 1u : 0u) << b2;
            mem[b2] = s ? 0.0f : m2;
        }
        s3p[(base_row + d_own) * NW + nchunk * 4 + nw_own] = sw;
        __syncthreads();
    }
}

// ---------------------------------------------------------------------------
// Kernel 3 v3: projection conv + BN on packed spikes -> fp32 output.
// Same 1-barrier-per-k-step double-buffer pipeline as kernel 1; X prefetch
// is just 2 packed u32 + one float4 of W per thread (6 regs). No
// launch_bounds second arg (see v2 post-mortem).
// ---------------------------------------------------------------------------
__global__ __launch_bounds__(256) void proj_kernel(
    const uint32_t* __restrict__ s3p,          // [BB*CC, NW] packed
    const float* __restrict__ W,               // [CC, CC]
    const float* __restrict__ bn_g,
    const float* __restrict__ bn_b,
    const float* __restrict__ bn_m,
    const float* __restrict__ bn_v,
    float* __restrict__ out)                   // [BB, CC, NN]
{
    __shared__ float Xs[2][16][132];
    __shared__ float Ws_s[2][16][68];

    const int tid = threadIdx.x;
    const int tx = tid & 15;
    const int ty = tid >> 4;
    const int n0 = blockIdx.x * 128;
    const int c0 = blockIdx.y * 64;
    const int b = blockIdx.z;

    float inv_c[4], add_c[4];
#pragma unroll
    for (int i = 0; i < 4; ++i) {
        int c = c0 + 4 * ty + i;
        float g = bn_g[3 * CC + c];
        float bt = bn_b[3 * CC + c];
        float m = bn_m[3 * CC + c];
        float v = bn_v[3 * CC + c];
        float inv = g / sqrtf(v + EPS);
        inv_c[i] = inv;
        add_c[i] = bt - m * inv;
    }

    const int wr  = tid >> 2;
    const int wkw = tid & 3;
    const int kkA = tid >> 5;
    const int colA = tid & 31;
    const int shA = 4 * (colA & 7);

    const float* Wrow = W + (size_t)(c0 + wr) * CC + 4 * wkw;
    const uint32_t* sp = s3p + (size_t)(b * CC) * NW + (n0 >> 5) + (colA >> 3);

    float acc[4][8];
#pragma unroll
    for (int i = 0; i < 4; ++i)
#pragma unroll
        for (int j = 0; j < 8; ++j) acc[i][j] = 0.0f;

    // ---- prologue: stage k0=0 into buf0 (latency exposed once) ----
    {
        uint32_t swA = sp[(size_t)kkA * NW];
        uint32_t swB = sp[(size_t)(8 + kkA) * NW];
        float4 wv4 = *(const float4*)&Wrow[0];
        float4 xv;
        xv.x = (float)((swA >> (shA + 0)) & 1u);
        xv.y = (float)((swA >> (shA + 1)) & 1u);
        xv.z = (float)((swA >> (shA + 2)) & 1u);
        xv.w = (float)((swA >> (shA + 3)) & 1u);
        *(float4*)&Xs[0][kkA][4 * colA] = xv;
        xv.x = (float)((swB >> (shA + 0)) & 1u);
        xv.y = (float)((swB >> (shA + 1)) & 1u);
        xv.z = (float)((swB >> (shA + 2)) & 1u);
        xv.w = (float)((swB >> (shA + 3)) & 1u);
        *(float4*)&Xs[0][8 + kkA][4 * colA] = xv;
        Ws_s[0][4 * wkw + 0][wr] = wv4.x;
        Ws_s[0][4 * wkw + 1][wr] = wv4.y;
        Ws_s[0][4 * wkw + 2][wr] = wv4.z;
        Ws_s[0][4 * wkw + 3][wr] = wv4.w;
    }
    __syncthreads();

    int cur = 0;
    for (int k0 = 0; k0 < CC; k0 += 16) {
        const int nxt = cur ^ 1;
        uint32_t swA, swB;
        float4 wv4;
        if (k0 + 16 < CC) {
            swA = sp[(size_t)(k0 + 16 + kkA) * NW];
            swB = sp[(size_t)(k0 + 24 + kkA) * NW];
            wv4 = *(const float4*)&Wrow[k0 + 16];
        }

#pragma unroll
        for (int kk = 0; kk < 16; ++kk) {
            float4 av  = *(float4*)&Ws_s[cur][kk][4 * ty];
            float4 xlo = *(float4*)&Xs[cur][kk][4 * tx];
            float4 xhi = *(float4*)&Xs[cur][kk][64 + 4 * tx];
            const float a[4]  = {av.x, av.y, av.z, av.w};
            const float xl[4] = {xlo.x, xlo.y, xlo.z, xlo.w};
            const float xh[4] = {xhi.x, xhi.y, xhi.z, xhi.w};
#pragma unroll
            for (int i = 0; i < 4; ++i) {
#pragma unroll
                for (int j = 0; j < 4; ++j) {
                    acc[i][j]     += a[i] * xl[j];
                    acc[i][4 + j] += a[i] * xh[j];
                }
            }
        }

        if (k0 + 16 < CC) {
            float4 xv;
            xv.x = (float)((swA >> (shA + 0)) & 1u);
            xv.y = (float)((swA >> (shA + 1)) & 1u);
            xv.z = (float)((swA >> (shA + 2)) & 1u);
            xv.w = (float)((swA >> (shA + 3)) & 1u);
            *(float4*)&Xs[nxt][kkA][4 * colA] = xv;
            xv.x = (float)((swB >> (shA + 0)) & 1u);
            xv.y = (float)((swB >> (shA + 1)) & 1u);
            xv.z = (float)((swB >> (shA + 2)) & 1u);
            xv.w = (float)((swB >> (shA + 3)) & 1u);
            *(float4*)&Xs[nxt][8 + kkA][4 * colA] = xv;
            Ws_s[nxt][4 * wkw + 0][wr] = wv4.x;
            Ws_s[nxt][4 * wkw + 1][wr] = wv4.y;
            Ws_s[nxt][4 * wkw + 2][wr] = wv4.z;
            Ws_s[nxt][4 * wkw + 3][wr] = wv4.w;
            __syncthreads();
            cur = nxt;
        }
    }

    float* ob = out + (size_t)b * CC * NN;
#pragma unroll
    for (int i = 0; i < 4; ++i) {
        int c = c0 + 4 * ty + i;
        float4 lo, hi;
        lo.x = acc[i][0] * inv_c[i] + add_c[i];
        lo.y = acc[i][1] * inv_c[i] + add_c[i];
        lo.z = acc[i][2] * inv_c[i] + add_c[i];
        lo.w = acc[i][3] * inv_c[i] + add_c[i];
        hi.x = acc[i][4] * inv_c[i] + add_c[i];
        hi.y = acc[i][5] * inv_c[i] + add_c[i];
        hi.z = acc[i][6] * inv_c[i] + add_c[i];
        hi.w = acc[i][7] * inv_c[i] + add_c[i];
        *(float4*)&ob[(size_t)c * NN + n0 + 4 * tx] = lo;
        *(float4*)&ob[(size_t)c * NN + n0 + 64 + 4 * tx] = hi;
    }
}

// ---------------------------------------------------------------------------
extern "C" void kernel_launch(void* const* d_in, const int* in_sizes, int n_in,
                              void* d_out, int out_size, void* d_ws, size_t ws_size,
                              hipStream_t stream) {
    const float* x     = (const float*)d_in[0];
    const float* wq    = (const float*)d_in[1];
    const float* wk    = (const float*)d_in[2];
    const float* wv    = (const float*)d_in[3];
    const float* wproj = (const float*)d_in[4];
    const float* bng   = (const float*)d_in[5];
    const float* bnb   = (const float*)d_in[6];
    const float* bnm   = (const float*)d_in[7];
    const float* bnv   = (const float*)d_in[8];

    const size_t PK = (size_t)BB * CC * NW;            // 2 MiB each
    uint32_t* qp  = (uint32_t*)d_ws;
    uint32_t* kp  = qp + PK;
    uint32_t* vp  = kp + PK;
    uint32_t* s3p = vp + PK;                           // total 8 MiB

    dim3 gconv(NN / 128, CC / 64, 3 * BE);             // z = w*16 + be
    conv_bn_lif_kernel<<<gconv, 256, 0, stream>>>(x, wq, wk, wv, bng, bnb, bnm, bnv,
                                                  qp, kp, vp);

    dim3 gattn(4, NH, BE);
    attn_lif_kernel<<<gattn, 256, 0, stream>>>(qp, kp, vp, s3p);

    dim3 gproj(NN / 128, CC / 64, BB);
    proj_kernel<<<gproj, 256, 0, stream>>>(s3p, wproj, bng, bnb, bnm, bnv, (float*)d_out);
}

// Round 3
// 1313.511 us; speedup vs baseline: 4.3913x; 1.2167x over previous
//
#include <hip/hip_runtime.h>
#include <hip/hip_bf16.h>
#include <stdint.h>

// Problem constants
#define TT 4
#define BE 16
#define BB 64          // TT * BE
#define CC 512
#define NN 512
#define NH 8
#define GD 64          // CC / NH
#define NW 16          // NN/32 packed words per (b,c) row
#define TAU 0.5f
#define THRESH 1.0f
#define SCALE 0.125f
#define EPS 1e-5f

// Direct global->LDS DMA, 16B per lane. LDS dest is wave-uniform base +
// lane*16 (linear); global src is per-lane.
#define GLL16(g, l)                                                        \
    __builtin_amdgcn_global_load_lds(                                      \
        (const __attribute__((address_space(1))) void*)(g),                \
        (__attribute__((address_space(3))) void*)(l), 16, 0, 0)

// ---------------------------------------------------------------------------
// Kernel 1 v4: 1x1-conv + BN + LIF -> bit-packed spikes.
// Lessons: v2 (launch_bounds 2nd arg -> 84 VGPR -> 16GB spill, 7x slower),
// v3 (1-barrier dbuf merged scheduling regions -> 164 VGPR -> occupancy
// halved at the 128-reg granule, 1.7x slower). So: keep v1's proven
// 2-barrier single-buffer skeleton (VGPR=128, 4 blocks/CU) and change only:
//   * X staged via global_load_lds (no VGPR round trip, shorter stage path)
//   * BK=32 (half the barrier pairs; ~2048 compute cycles per stage)
//   * sched_barrier(0) between the two 16-kk halves to fence ds_read
//     hoisting (guards the 128-VGPR cliff).
// Block tile: 64 c-rows x 128 n-cols, 256 threads, micro-tile 4x8.
// ---------------------------------------------------------------------------
__global__ __launch_bounds__(256) void conv_bn_lif_kernel(
    const float* __restrict__ x,      // [BB, CC, NN]
    const float* __restrict__ Wq,     // [CC, CC] (out, in)
    const float* __restrict__ Wk,
    const float* __restrict__ Wv,
    const float* __restrict__ bn_g,   // [4, CC]
    const float* __restrict__ bn_b,
    const float* __restrict__ bn_m,
    const float* __restrict__ bn_v,
    uint32_t* __restrict__ qp,        // [BB*CC, NW] packed
    uint32_t* __restrict__ kp,
    uint32_t* __restrict__ vp)
{
    // Xs UNPADDED [32][128]: linear layout required by global_load_lds.
    // float4 reads at 4*tx (+64) are 2-way bank aliasing max = free.
    __shared__ float Xs[32][128];
    __shared__ float Ws_s[32][68];

    const int tid = threadIdx.x;
    const int tx = tid & 15;          // col group
    const int ty = tid >> 4;          // row group: rows c0+4ty..+3
    const int n0 = blockIdx.x * 128;
    const int c0 = blockIdx.y * 64;
    const int z  = blockIdx.z;
    const int be = z & (BE - 1);
    const int w  = z >> 4;            // 0=q 1=k 2=v

    const float* W = (w == 0) ? Wq : (w == 1) ? Wk : Wv;
    uint32_t* outp = (w == 0) ? qp : (w == 1) ? kp : vp;

    float inv_c[4], add_c[4];
#pragma unroll
    for (int i = 0; i < 4; ++i) {
        int c = c0 + 4 * ty + i;
        float g = bn_g[w * CC + c];
        float b = bn_b[w * CC + c];
        float m = bn_m[w * CC + c];
        float v = bn_v[w * CC + c];
        float inv = g / sqrtf(v + EPS);
        inv_c[i] = inv;
        add_c[i] = b - m * inv;
    }

    float mem[4][8];
#pragma unroll
    for (int i = 0; i < 4; ++i)
#pragma unroll
        for (int j = 0; j < 8; ++j) mem[i][j] = 0.0f;

    // W staging mapping (reg->LDS transpose)
    const int wr  = tid >> 2;         // W row within tile (0..63)
    const int wkw = tid & 3;          // W float4 along K (k = 4*wkw, 16+4*wkw)
    const float* Wrow = W + (size_t)(c0 + wr) * CC;

    // X gll mapping: wave wid stages rows {2wid, 2wid+1} + 8s, s=0..3;
    // lane covers 16B at col 4*(lane&31).
    const int lane = tid & 63;
    const int wid  = tid >> 6;
    const int xrow_l = 2 * wid + (lane >> 5);
    const int xcol   = 4 * (lane & 31);

    for (int t = 0; t < TT; ++t) {
        const int b = t * BE + be;
        const float* xg = x + (size_t)b * CC * NN + n0 + xcol;

        float acc[4][8];
#pragma unroll
        for (int i = 0; i < 4; ++i)
#pragma unroll
            for (int j = 0; j < 8; ++j) acc[i][j] = 0.0f;

        for (int k0 = 0; k0 < CC; k0 += 32) {
            __syncthreads();   // all readers of Xs/Ws done (prev stage / prev t)

            // W loads first so the ds_writes below wait only on these
            // (vmcnt is in-order; glls issued after).
            float4 w0 = *(const float4*)&Wrow[k0 + 4 * wkw];
            float4 w1 = *(const float4*)&Wrow[k0 + 16 + 4 * wkw];

            // X: 4 wave-glls, each 1KB = 2 rows of the 32x128 tile
            GLL16(xg + (size_t)(k0 + xrow_l +  0) * NN, &Xs[2 * wid +  0][0]);
            GLL16(xg + (size_t)(k0 + xrow_l +  8) * NN, &Xs[2 * wid +  8][0]);
            GLL16(xg + (size_t)(k0 + xrow_l + 16) * NN, &Xs[2 * wid + 16][0]);
            GLL16(xg + (size_t)(k0 + xrow_l + 24) * NN, &Xs[2 * wid + 24][0]);

            Ws_s[4 * wkw + 0][wr] = w0.x;
            Ws_s[4 * wkw + 1][wr] = w0.y;
            Ws_s[4 * wkw + 2][wr] = w0.z;
            Ws_s[4 * wkw + 3][wr] = w0.w;
            Ws_s[16 + 4 * wkw + 0][wr] = w1.x;
            Ws_s[16 + 4 * wkw + 1][wr] = w1.y;
            Ws_s[16 + 4 * wkw + 2][wr] = w1.z;
            Ws_s[16 + 4 * wkw + 3][wr] = w1.w;

            __syncthreads();   // drains vmcnt (glls) + lgkm (W writes)

#pragma unroll
            for (int kk = 0; kk < 16; ++kk) {
                float4 av  = *(float4*)&Ws_s[kk][4 * ty];      // 4 bcast reads
                float4 xlo = *(float4*)&Xs[kk][4 * tx];        // 2-way
                float4 xhi = *(float4*)&Xs[kk][64 + 4 * tx];   // 2-way
                const float a[4]  = {av.x, av.y, av.z, av.w};
                const float xl[4] = {xlo.x, xlo.y, xlo.z, xlo.w};
                const float xh[4] = {xhi.x, xhi.y, xhi.z, xhi.w};
#pragma unroll
                for (int i = 0; i < 4; ++i) {
#pragma unroll
                    for (int j = 0; j < 4; ++j) {
                        acc[i][j]     += a[i] * xl[j];
                        acc[i][4 + j] += a[i] * xh[j];
                    }
                }
            }
            // fence ds_read hoisting between halves: keeps live-range profile
            // (and thus VGPR count) at v1's level
            __builtin_amdgcn_sched_barrier(0);
#pragma unroll
            for (int kk = 16; kk < 32; ++kk) {
                float4 av  = *(float4*)&Ws_s[kk][4 * ty];
                float4 xlo = *(float4*)&Xs[kk][4 * tx];
                float4 xhi = *(float4*)&Xs[kk][64 + 4 * tx];
                const float a[4]  = {av.x, av.y, av.z, av.w};
                const float xl[4] = {xlo.x, xlo.y, xlo.z, xlo.w};
                const float xh[4] = {xhi.x, xhi.y, xhi.z, xhi.w};
#pragma unroll
                for (int i = 0; i < 4; ++i) {
#pragma unroll
                    for (int j = 0; j < 4; ++j) {
                        acc[i][j]     += a[i] * xl[j];
                        acc[i][4 + j] += a[i] * xh[j];
                    }
                }
            }
        }

        // epilogue: BN + LIF -> two nibbles/row -> octet shfl-OR -> global word
#pragma unroll
        for (int i = 0; i < 4; ++i) {
            uint32_t nibLo = 0, nibHi = 0;
#pragma unroll
            for (int j = 0; j < 4; ++j) {
                float y = acc[i][j] * inv_c[i] + add_c[i];
                float m2 = mem[i][j] * TAU + y;
                bool s = m2 > THRESH;
                nibLo |= (s ? 1u : 0u) << j;
                mem[i][j] = s ? 0.0f : m2;

                float y2 = acc[i][4 + j] * inv_c[i] + add_c[i];
                float m22 = mem[i][4 + j] * TAU + y2;
                bool s2 = m22 > THRESH;
                nibHi |= (s2 ? 1u : 0u) << j;
                mem[i][4 + j] = s2 ? 0.0f : m22;
            }
            const size_t rowbase = (size_t)(b * CC + c0 + 4 * ty + i) * NW + (n0 >> 5);
            uint32_t wlo = nibLo << (4 * (tx & 7));
            wlo |= (uint32_t)__shfl_xor((int)wlo, 1);
            wlo |= (uint32_t)__shfl_xor((int)wlo, 2);
            wlo |= (uint32_t)__shfl_xor((int)wlo, 4);
            uint32_t whi = nibHi << (4 * (tx & 7));
            whi |= (uint32_t)__shfl_xor((int)whi, 1);
            whi |= (uint32_t)__shfl_xor((int)whi, 2);
            whi |= (uint32_t)__shfl_xor((int)whi, 4);
            if ((tx & 7) == 0) {
                outp[rowbase + (tx >> 3)] = wlo;
                outp[rowbase + 2 + (tx >> 3)] = whi;
            }
        }
    }
}

// ---------------------------------------------------------------------------
// Kernel 2: fused attention + LIF3 on packed spikes (unchanged, verified).
// ---------------------------------------------------------------------------
__global__ __launch_bounds__(256) void attn_lif_kernel(
    const uint32_t* __restrict__ qp,
    const uint32_t* __restrict__ kp,
    const uint32_t* __restrict__ vp,
    uint32_t* __restrict__ s3p)
{
    __shared__ uint32_t kL[64][NW + 1];
    __shared__ uint32_t vL[64][NW + 1];
    __shared__ float    Msh[64][64 + 1];
    __shared__ uint32_t qL[64][5];

    const int tid = threadIdx.x;
    const int nchunk = blockIdx.x;
    const int h = blockIdx.y;
    const int be = blockIdx.z;
    const int d_own = tid >> 2;
    const int nw_own = tid & 3;

    float mem[32];
#pragma unroll
    for (int i = 0; i < 32; ++i) mem[i] = 0.0f;

    for (int t = 0; t < TT; ++t) {
        const int b = t * BE + be;
        const size_t base_row = (size_t)(b * CC + h * GD);

        for (int i = tid; i < 64 * NW; i += 256) {
            int r = i >> 4;
            int w = i & (NW - 1);
            kL[r][w] = kp[(base_row + r) * NW + w];
            vL[r][w] = vp[(base_row + r) * NW + w];
        }
        {
            int r = tid >> 2;
            int w = tid & 3;
            qL[r][w] = qp[(base_row + r) * NW + nchunk * 4 + w];
        }
        __syncthreads();

        for (int e = tid; e < 64 * 64; e += 256) {
            int d = e >> 6;
            int dp = e & 63;
            int s = 0;
#pragma unroll
            for (int w = 0; w < NW; ++w) s += __popc(vL[d][w] & kL[dp][w]);
            Msh[d][dp] = (float)s;
        }
        __syncthreads();

        float acc[32];
#pragma unroll
        for (int i = 0; i < 32; ++i) acc[i] = 0.0f;

        for (int dp = 0; dp < 64; ++dp) {
            float Mv = Msh[d_own][dp];
            uint32_t w = qL[dp][nw_own];
#pragma unroll
            for (int b2 = 0; b2 < 32; ++b2) {
                acc[b2] += ((w >> b2) & 1u) ? Mv : 0.0f;
            }
        }

        uint32_t sw = 0;
#pragma unroll
        for (int b2 = 0; b2 < 32; ++b2) {
            float m2 = mem[b2] * TAU + SCALE * acc[b2];
            bool s = m2 > THRESH;
            sw |= (s ? 1u : 0u) << b2;
            mem[b2] = s ? 0.0f : m2;
        }
        s3p[(base_row + d_own) * NW + nchunk * 4 + nw_own] = sw;
        __syncthreads();
    }
}

// ---------------------------------------------------------------------------
// Kernel 3 v3 (kept from round 2 — improved there, VGPR under the cliff):
// projection conv + BN on packed spikes -> fp32 output. Double-buffered,
// 1 barrier per k-step, reg-staged (tiny prefetch state).
// ---------------------------------------------------------------------------
__global__ __launch_bounds__(256) void proj_kernel(
    const uint32_t* __restrict__ s3p,          // [BB*CC, NW] packed
    const float* __restrict__ W,               // [CC, CC]
    const float* __restrict__ bn_g,
    const float* __restrict__ bn_b,
    const float* __restrict__ bn_m,
    const float* __restrict__ bn_v,
    float* __restrict__ out)                   // [BB, CC, NN]
{
    __shared__ float Xs[2][16][132];
    __shared__ float Ws_s[2][16][68];

    const int tid = threadIdx.x;
    const int tx = tid & 15;
    const int ty = tid >> 4;
    const int n0 = blockIdx.x * 128;
    const int c0 = blockIdx.y * 64;
    const int b = blockIdx.z;

    float inv_c[4], add_c[4];
#pragma unroll
    for (int i = 0; i < 4; ++i) {
        int c = c0 + 4 * ty + i;
        float g = bn_g[3 * CC + c];
        float bt = bn_b[3 * CC + c];
        float m = bn_m[3 * CC + c];
        float v = bn_v[3 * CC + c];
        float inv = g / sqrtf(v + EPS);
        inv_c[i] = inv;
        add_c[i] = bt - m * inv;
    }

    const int wr  = tid >> 2;
    const int wkw = tid & 3;
    const int kkA = tid >> 5;
    const int colA = tid & 31;
    const int shA = 4 * (colA & 7);

    const float* Wrow = W + (size_t)(c0 + wr) * CC + 4 * wkw;
    const uint32_t* sp = s3p + (size_t)(b * CC) * NW + (n0 >> 5) + (colA >> 3);

    float acc[4][8];
#pragma unroll
    for (int i = 0; i < 4; ++i)
#pragma unroll
        for (int j = 0; j < 8; ++j) acc[i][j] = 0.0f;

    // ---- prologue: stage k0=0 into buf0 (latency exposed once) ----
    {
        uint32_t swA = sp[(size_t)kkA * NW];
        uint32_t swB = sp[(size_t)(8 + kkA) * NW];
        float4 wv4 = *(const float4*)&Wrow[0];
        float4 xv;
        xv.x = (float)((swA >> (shA + 0)) & 1u);
        xv.y = (float)((swA >> (shA + 1)) & 1u);
        xv.z = (float)((swA >> (shA + 2)) & 1u);
        xv.w = (float)((swA >> (shA + 3)) & 1u);
        *(float4*)&Xs[0][kkA][4 * colA] = xv;
        xv.x = (float)((swB >> (shA + 0)) & 1u);
        xv.y = (float)((swB >> (shA + 1)) & 1u);
        xv.z = (float)((swB >> (shA + 2)) & 1u);
        xv.w = (float)((swB >> (shA + 3)) & 1u);
        *(float4*)&Xs[0][8 + kkA][4 * colA] = xv;
        Ws_s[0][4 * wkw + 0][wr] = wv4.x;
        Ws_s[0][4 * wkw + 1][wr] = wv4.y;
        Ws_s[0][4 * wkw + 2][wr] = wv4.z;
        Ws_s[0][4 * wkw + 3][wr] = wv4.w;
    }
    __syncthreads();

    int cur = 0;
    for (int k0 = 0; k0 < CC; k0 += 16) {
        const int nxt = cur ^ 1;
        uint32_t swA, swB;
        float4 wv4;
        if (k0 + 16 < CC) {
            swA = sp[(size_t)(k0 + 16 + kkA) * NW];
            swB = sp[(size_t)(k0 + 24 + kkA) * NW];
            wv4 = *(const float4*)&Wrow[k0 + 16];
        }

#pragma unroll
        for (int kk = 0; kk < 16; ++kk) {
            float4 av  = *(float4*)&Ws_s[cur][kk][4 * ty];
            float4 xlo = *(float4*)&Xs[cur][kk][4 * tx];
            float4 xhi = *(float4*)&Xs[cur][kk][64 + 4 * tx];
            const float a[4]  = {av.x, av.y, av.z, av.w};
            const float xl[4] = {xlo.x, xlo.y, xlo.z, xlo.w};
            const float xh[4] = {xhi.x, xhi.y, xhi.z, xhi.w};
#pragma unroll
            for (int i = 0; i < 4; ++i) {
#pragma unroll
                for (int j = 0; j < 4; ++j) {
                    acc[i][j]     += a[i] * xl[j];
                    acc[i][4 + j] += a[i] * xh[j];
                }
            }
        }

        if (k0 + 16 < CC) {
            float4 xv;
            xv.x = (float)((swA >> (shA + 0)) & 1u);
            xv.y = (float)((swA >> (shA + 1)) & 1u);
            xv.z = (float)((swA >> (shA + 2)) & 1u);
            xv.w = (float)((swA >> (shA + 3)) & 1u);
            *(float4*)&Xs[nxt][kkA][4 * colA] = xv;
            xv.x = (float)((swB >> (shA + 0)) & 1u);
            xv.y = (float)((swB >> (shA + 1)) & 1u);
            xv.z = (float)((swB >> (shA + 2)) & 1u);
            xv.w = (float)((swB >> (shA + 3)) & 1u);
            *(float4*)&Xs[nxt][8 + kkA][4 * colA] = xv;
            Ws_s[nxt][4 * wkw + 0][wr] = wv4.x;
            Ws_s[nxt][4 * wkw + 1][wr] = wv4.y;
            Ws_s[nxt][4 * wkw + 2][wr] = wv4.z;
            Ws_s[nxt][4 * wkw + 3][wr] = wv4.w;
            __syncthreads();
            cur = nxt;
        }
    }

    float* ob = out + (size_t)b * CC * NN;
#pragma unroll
    for (int i = 0; i < 4; ++i) {
        int c = c0 + 4 * ty + i;
        float4 lo, hi;
        lo.x = acc[i][0] * inv_c[i] + add_c[i];
        lo.y = acc[i][1] * inv_c[i] + add_c[i];
        lo.z = acc[i][2] * inv_c[i] + add_c[i];
        lo.w = acc[i][3] * inv_c[i] + add_c[i];
        hi.x = acc[i][4] * inv_c[i] + add_c[i];
        hi.y = acc[i][5] * inv_c[i] + add_c[i];
        hi.z = acc[i][6] * inv_c[i] + add_c[i];
        hi.w = acc[i][7] * inv_c[i] + add_c[i];
        *(float4*)&ob[(size_t)c * NN + n0 + 4 * tx] = lo;
        *(float4*)&ob[(size_t)c * NN + n0 + 64 + 4 * tx] = hi;
    }
}

// ---------------------------------------------------------------------------
extern "C" void kernel_launch(void* const* d_in, const int* in_sizes, int n_in,
                              void* d_out, int out_size, void* d_ws, size_t ws_size,
                              hipStream_t stream) {
    const float* x     = (const float*)d_in[0];
    const float* wq    = (const float*)d_in[1];
    const float* wk    = (const float*)d_in[2];
    const float* wv    = (const float*)d_in[3];
    const float* wproj = (const float*)d_in[4];
    const float* bng   = (const float*)d_in[5];
    const float* bnb   = (const float*)d_in[6];
    const float* bnm   = (const float*)d_in[7];
    const float* bnv   = (const float*)d_in[8];

    const size_t PK = (size_t)BB * CC * NW;            // 2 MiB each
    uint32_t* qp  = (uint32_t*)d_ws;
    uint32_t* kp  = qp + PK;
    uint32_t* vp  = kp + PK;
    uint32_t* s3p = vp + PK;                           // total 8 MiB

    dim3 gconv(NN / 128, CC / 64, 3 * BE);             // z = w*16 + be
    conv_bn_lif_kernel<<<gconv, 256, 0, stream>>>(x, wq, wk, wv, bng, bnb, bnm, bnv,
                                                  qp, kp, vp);

    dim3 gattn(4, NH, BE);
    attn_lif_kernel<<<gattn, 256, 0, stream>>>(qp, kp, vp, s3p);

    dim3 gproj(NN / 128, CC / 64, BB);
    proj_kernel<<<gproj, 256, 0, stream>>>(s3p, wproj, bng, bnb, bnm, bnv, (float*)d_out);
}